// Round 1
// baseline (431.003 us; speedup 1.0000x reference)
//
#include <hip/hip_runtime.h>
#include <hip/hip_bf16.h>
#include <stdint.h>

#define N 8192
#define FIN 256
#define FOUT 64
#define WAVES 8                  // waves per block = j-slices per 16-row group
#define JLEN (N / WAVES)         // 1024 columns per wave

typedef __attribute__((ext_vector_type(8))) short s8v;
typedef __attribute__((ext_vector_type(4))) float f4v;

// float -> bf16 bits, round-to-nearest-even
__device__ __forceinline__ uint32_t f2bf(float f) {
  uint32_t u = __float_as_uint(f);
  return (u + 0x7FFFu + ((u >> 16) & 1u)) >> 16;
}

// Kernel A: Wh = h@W (fp32 in regs), f1 = (Wh@a1)*log2e, f2 = (Wh@a2)*log2e,
// store WhT bf16 [64][8192]. 4 rows/wave, 4 waves/block -> 512 blocks.
// f1/f2 pre-scaled by log2(e): lrelu commutes with positive scale, so the
// main kernel computes exp(lrelu(f1+f2)) as a single v_exp_f32 (exp2).
__global__ __launch_bounds__(256) void gat_prep(
    const float* __restrict__ h, const float* __restrict__ W,
    const float* __restrict__ a,
    float* __restrict__ f1, float* __restrict__ f2,
    uint16_t* __restrict__ whT)
{
  const int c = threadIdx.x & 63;            // output feature
  const int wave = threadIdx.x >> 6;
  const int i0 = blockIdx.x * 16 + wave * 4; // 4 rows per wave
  float acc[4] = {0.f, 0.f, 0.f, 0.f};
  #pragma unroll 8
  for (int k = 0; k < FIN; ++k) {
    float wv = W[k * FOUT + c];              // coalesced across lanes
    #pragma unroll
    for (int r = 0; r < 4; ++r)              // h index wave-uniform -> s_load
      acc[r] += h[(size_t)(i0 + r) * FIN + k] * wv;
  }
  // lane c holds Wh[i0+r][c] == WhT[c][i0+r]: pack 4 bf16, one 8B store
  uint32_t b0 = f2bf(acc[0]), b1 = f2bf(acc[1]), b2 = f2bf(acc[2]), b3 = f2bf(acc[3]);
  int2 pk;
  pk.x = (int)(b0 | (b1 << 16));
  pk.y = (int)(b2 | (b3 << 16));
  *(int2*)(whT + (size_t)c * N + i0) = pk;

  const float a1 = a[c], a2 = a[FOUT + c];
  const float LOG2E = 1.4426950408889634f;
  #pragma unroll
  for (int r = 0; r < 4; ++r) {
    float v1 = acc[r] * a1;
    float v2 = acc[r] * a2;
    #pragma unroll
    for (int m = 32; m > 0; m >>= 1) {
      v1 += __shfl_xor(v1, m, 64);
      v2 += __shfl_xor(v2, m, 64);
    }
    if (c == 0) { f1[i0 + r] = v1 * LOG2E; f2[i0 + r] = v2 * LOG2E; }
  }
}

// Build one MFMA A-fragment (8 bf16 attention weights) from pre-loaded regs.
// f1v/g are pre-scaled by log2e, so weight = exp2(max(e, 0.2e)).
__device__ __forceinline__ s8v make_afrag(float f1v, int4 c0, int4 c1,
                                          float4 g0, float4 g1, float& den) {
  float e0 = f1v + g0.x; e0 = fmaxf(e0, 0.2f * e0); float w0 = (c0.x > 0) ? __builtin_exp2f(e0) : 0.f;
  float e1 = f1v + g0.y; e1 = fmaxf(e1, 0.2f * e1); float w1 = (c0.y > 0) ? __builtin_exp2f(e1) : 0.f;
  float e2 = f1v + g0.z; e2 = fmaxf(e2, 0.2f * e2); float w2 = (c0.z > 0) ? __builtin_exp2f(e2) : 0.f;
  float e3 = f1v + g0.w; e3 = fmaxf(e3, 0.2f * e3); float w3 = (c0.w > 0) ? __builtin_exp2f(e3) : 0.f;
  float e4 = f1v + g1.x; e4 = fmaxf(e4, 0.2f * e4); float w4 = (c1.x > 0) ? __builtin_exp2f(e4) : 0.f;
  float e5 = f1v + g1.y; e5 = fmaxf(e5, 0.2f * e5); float w5 = (c1.y > 0) ? __builtin_exp2f(e5) : 0.f;
  float e6 = f1v + g1.z; e6 = fmaxf(e6, 0.2f * e6); float w6 = (c1.z > 0) ? __builtin_exp2f(e6) : 0.f;
  float e7 = f1v + g1.w; e7 = fmaxf(e7, 0.2f * e7); float w7 = (c1.w > 0) ? __builtin_exp2f(e7) : 0.f;
  uint32_t b0 = f2bf(w0), b1 = f2bf(w1), b2 = f2bf(w2), b3 = f2bf(w3);
  uint32_t b4 = f2bf(w4), b5 = f2bf(w5), b6 = f2bf(w6), b7 = f2bf(w7);
  // denominator from the bf16-rounded weights (consistent with MFMA numerator)
  den += __uint_as_float(b0 << 16) + __uint_as_float(b1 << 16)
       + __uint_as_float(b2 << 16) + __uint_as_float(b3 << 16)
       + __uint_as_float(b4 << 16) + __uint_as_float(b5 << 16)
       + __uint_as_float(b6 << 16) + __uint_as_float(b7 << 16);
  union { s8v v; uint32_t u[4]; } r;
  r.u[0] = b0 | (b1 << 16);
  r.u[1] = b2 | (b3 << 16);
  r.u[2] = b4 | (b5 << 16);
  r.u[3] = b6 | (b7 << 16);
  return r.v;
}

// Kernel B (fused): one block = 16 rows x full N. 8 waves, each owns a
// 1024-col slice (barrier-free main loop), then LDS reduce + divide + ELU.
// adj is double-buffered in two NAMED register sets (no prefetch->current
// copies -> ~32 fewer live VGPRs); f2 slice staged in LDS (own-wave only,
// no barrier); whT stays L2-hot.
__global__ __launch_bounds__(512, 4) void gat_fused(
    const int* __restrict__ adj, const float* __restrict__ f1,
    const float* __restrict__ f2, const uint16_t* __restrict__ whT,
    float* __restrict__ out)
{
  __shared__ __align__(16) float lds_f2[WAVES][JLEN];     // 32 KB
  __shared__ __align__(16) float lds_num[WAVES][16][64];  // 32 KB
  __shared__ float lds_den[WAVES][16];                    // 512 B

  const int t = threadIdx.x;
  const int w = t >> 6;
  const int lane = t & 63;
  const int i0 = blockIdx.x * 16;
  const int jb = w * JLEN;
  const int m  = lane & 15;                 // A row / C col
  const int kg = lane >> 4;                 // k-group (8 elems each)

  const float f1v = f1[i0 + m];
  const int*      ap  = adj + (size_t)(i0 + m) * N + jb + kg * 8;
  const uint16_t* bp0 = whT + (size_t)m * N + jb + kg * 8;

  // prologue: issue chunk-0 adj loads first so HBM latency overlaps staging
  int4 A0 = *(const int4*)(ap);
  int4 A1 = *(const int4*)(ap + 4);
  int4 A2 = *(const int4*)(ap + 32);
  int4 A3 = *(const int4*)(ap + 36);

  // stage this wave's 4 KB f2 slice into LDS (read only by this wave)
  #pragma unroll
  for (int q = 0; q < 4; ++q)
    *(float4*)&lds_f2[w][q * 256 + lane * 4] =
        *(const float4*)&f2[jb + q * 256 + lane * 4];

  const float4* lf = (const float4*)&lds_f2[w][0];
  const int kg2 = kg * 2;

  f4v acc0 = {0.f, 0.f, 0.f, 0.f};
  f4v acc1 = acc0, acc2 = acc0, acc3 = acc0;
  float den = 0.f;

  int4 B0, B1, B2, B3;

#define COMPUTE(C0, C1, C2, C3, J) do {                                     \
    const uint16_t* bp = bp0 + (J);                                         \
    s8v b00 = *(const s8v*)(bp);                                            \
    s8v b01 = *(const s8v*)(bp + 32);                                       \
    s8v b10 = *(const s8v*)(bp + 16 * N);                                   \
    s8v b11 = *(const s8v*)(bp + 16 * N + 32);                              \
    s8v b20 = *(const s8v*)(bp + 32 * N);                                   \
    s8v b21 = *(const s8v*)(bp + 32 * N + 32);                              \
    s8v b30 = *(const s8v*)(bp + 48 * N);                                   \
    s8v b31 = *(const s8v*)(bp + 48 * N + 32);                              \
    float4 g0 = lf[((J) >> 2) + kg2];                                       \
    float4 g1 = lf[((J) >> 2) + kg2 + 1];                                   \
    float4 g2 = lf[((J) >> 2) + kg2 + 8];                                   \
    float4 g3 = lf[((J) >> 2) + kg2 + 9];                                   \
    s8v a0 = make_afrag(f1v, C0, C1, g0, g1, den);                          \
    s8v a1 = make_afrag(f1v, C2, C3, g2, g3, den);                          \
    acc0 = __builtin_amdgcn_mfma_f32_16x16x32_bf16(a0, b00, acc0, 0, 0, 0); \
    acc0 = __builtin_amdgcn_mfma_f32_16x16x32_bf16(a1, b01, acc0, 0, 0, 0); \
    acc1 = __builtin_amdgcn_mfma_f32_16x16x32_bf16(a0, b10, acc1, 0, 0, 0); \
    acc1 = __builtin_amdgcn_mfma_f32_16x16x32_bf16(a1, b11, acc1, 0, 0, 0); \
    acc2 = __builtin_amdgcn_mfma_f32_16x16x32_bf16(a0, b20, acc2, 0, 0, 0); \
    acc2 = __builtin_amdgcn_mfma_f32_16x16x32_bf16(a1, b21, acc2, 0, 0, 0); \
    acc3 = __builtin_amdgcn_mfma_f32_16x16x32_bf16(a0, b30, acc3, 0, 0, 0); \
    acc3 = __builtin_amdgcn_mfma_f32_16x16x32_bf16(a1, b31, acc3, 0, 0, 0); \
  } while (0)

  // 16 chunks of 64 cols, processed 2 per iteration with alternating A/B
  // register sets: depth-1 prefetch with no register copies.
  #pragma unroll 1
  for (int jc2 = 0; jc2 < 8; ++jc2) {
    const int j0 = jc2 * 128;
    B0 = *(const int4*)(ap + j0 + 64);
    B1 = *(const int4*)(ap + j0 + 68);
    B2 = *(const int4*)(ap + j0 + 96);
    B3 = *(const int4*)(ap + j0 + 100);
    COMPUTE(A0, A1, A2, A3, j0);
    if (jc2 < 7) {
      A0 = *(const int4*)(ap + j0 + 128);
      A1 = *(const int4*)(ap + j0 + 132);
      A2 = *(const int4*)(ap + j0 + 160);
      A3 = *(const int4*)(ap + j0 + 164);
    }
    COMPUTE(B0, B1, B2, B3, j0 + 64);
  }
#undef COMPUTE

  // den: sum across the 4 k-groups of this row (lanes m, m+16, m+32, m+48)
  den += __shfl_xor(den, 16, 64);
  den += __shfl_xor(den, 32, 64);

  // per-wave partials to LDS; C/D layout: col = lane&15, row = (lane>>4)*4+reg
  float* np = &lds_num[w][0][0];
  #pragma unroll
  for (int r = 0; r < 4; ++r) {
    int row = kg * 4 + r;
    np[row * 64 +      m] = acc0[r];
    np[row * 64 + 16 + m] = acc1[r];
    np[row * 64 + 32 + m] = acc2[r];
    np[row * 64 + 48 + m] = acc3[r];
  }
  if (lane < 16) lds_den[w][m] = den;
  __syncthreads();

  // reduce 8 wave-partials, divide, ELU. 512 threads x 2 rows each.
  const int col = t & 63;
  const int r0 = t >> 6;                    // 0..7
  #pragma unroll
  for (int hh = 0; hh < 2; ++hh) {
    const int row = r0 + hh * 8;
    float num = 0.f, dsum = 0.f;
    #pragma unroll
    for (int q = 0; q < WAVES; ++q) {
      num  += lds_num[q][row][col];         // 2-way bank alias: free
      dsum += lds_den[q][row];              // broadcast
    }
    float hp = num / dsum;
    out[(size_t)(i0 + row) * 64 + col] = (hp > 0.f) ? hp : (__expf(hp) - 1.f);
  }
}

extern "C" void kernel_launch(void* const* d_in, const int* in_sizes, int n_in,
                              void* d_out, int out_size, void* d_ws, size_t ws_size,
                              hipStream_t stream) {
  const float* h   = (const float*)d_in[0];
  const int*   adj = (const int*)d_in[1];
  const float* W   = (const float*)d_in[2];
  const float* a   = (const float*)d_in[3];
  float* out = (float*)d_out;

  float* f1 = (float*)d_ws;                     // 8192 f32
  float* f2 = f1 + N;                           // 8192 f32
  uint16_t* whT = (uint16_t*)(f2 + N);          // 64*8192 bf16 = 1 MB

  gat_prep<<<N / 16, 256, 0, stream>>>(h, W, a, f1, f2, whT);
  gat_fused<<<N / 16, 512, 0, stream>>>(adj, f1, f2, whT, out);
}